// Round 5
// baseline (116.963 us; speedup 1.0000x reference)
//
#include <hip/hip_runtime.h>
#include <math.h>

// BCE + distance-correlation loss, N=8192 fp32.
//
// Expansion (raw weights w, W=sum w, s=N/W):
//   S_XY = s^2*T1xy - (2 s^3/N)*sum_i w_i RX_i RY_i + (s^4/N^2)*CX*CY
//   T1ab = sum_ij w_i w_j |x_i-x_j||e_i-e_j|        (needs N^2)
//   T1aa = sum_ij w_i w_j (x_i-x_j)^2 = 2(W*Sxx - Sx^2)   (closed form!)
//   T1bb = 2(W*See - Se^2)
//   RX_i = sum_j w_j |x_i-x_j|  (N^2, row sums), CX = sum_i w_i RX_i
// kf: one N^2 pass -> T1ab block-partials + RA/RB j-split partials (no atomics).
// kg1: 32 blocks -> all 12 scalar sums (BCE, W, moments, RA/RB products).
// kg2: 1 block -> combine + output. No memsets, no atomics, deterministic.
//
// ws: double tpart[1024] @0; float RAp[128][N] @16K; float RBp[128][N];
//     double spart[32][12] @16K+8M.

#define BLK  256
#define RPT  4     // rows/thread -> i-tile 1024
#define JLEN 64    // j-chunk per block -> 128 j-splits
#define NSC  12

__device__ inline double waveReduceD(double v) {
    for (int off = 32; off > 0; off >>= 1) v += __shfl_down(v, off, 64);
    return v;
}

// valid in threadIdx.x==0
__device__ inline double blockReduceD(double v, double* lds) {
    int lane = threadIdx.x & 63, wid = threadIdx.x >> 6;
    v = waveReduceD(v);
    if (lane == 0) lds[wid] = v;
    __syncthreads();
    double r = 0.0;
    if (wid == 0) {
        int nw = blockDim.x >> 6;
        r = (lane < nw) ? lds[lane] : 0.0;
        r = waveReduceD(r);
    }
    __syncthreads();
    return r;
}

// N^2 pass. grid = (n/(BLK*RPT), n/JLEN).
__global__ __launch_bounds__(BLK) void kf(
        const float* __restrict__ x, const float* __restrict__ e,
        const float* __restrict__ w, int n, double* __restrict__ tpart,
        float* __restrict__ RAp, float* __restrict__ RBp) {
    __shared__ float xs[JLEN], es[JLEN], wsh[JLEN];
    __shared__ double lds[BLK / 64];
    int t = threadIdx.x;
    int tj = blockIdx.y;
    int j0 = tj * JLEN;
    if (t < JLEN) {
        xs[t] = x[j0 + t]; es[t] = e[j0 + t]; wsh[t] = w[j0 + t];
    }
    __syncthreads();

    int i0 = blockIdx.x * (BLK * RPT) + t;
    float xi[RPT], ei[RPT], ra[RPT], rb[RPT], ab[RPT];
#pragma unroll
    for (int r = 0; r < RPT; ++r) {
        int i = i0 + r * BLK;
        xi[r] = x[i]; ei[r] = e[i];
        ra[r] = 0.f; rb[r] = 0.f; ab[r] = 0.f;
    }

#pragma unroll 4
    for (int k = 0; k < JLEN; ++k) {
        float xj = xs[k], ej = es[k], wj = wsh[k];   // LDS broadcast, conflict-free
#pragma unroll
        for (int r = 0; r < RPT; ++r) {
            float a = fabsf(xi[r] - xj);
            float b = fabsf(ei[r] - ej);
            ra[r] = fmaf(wj, a, ra[r]);
            rb[r] = fmaf(wj, b, rb[r]);
            ab[r] = fmaf(wj, a * b, ab[r]);          // w_i applied below
        }
    }

    double tab = 0.0;
#pragma unroll
    for (int r = 0; r < RPT; ++r) {
        int i = i0 + r * BLK;
        tab += (double)(w[i] * ab[r]);
        RAp[(size_t)tj * n + i] = ra[r];             // plain stores, coalesced
        RBp[(size_t)tj * n + i] = rb[r];
    }
    tab = blockReduceD(tab, lds);
    if (t == 0) tpart[blockIdx.y * gridDim.x + blockIdx.x] = tab;
}

// Per-i scalar sums. grid = n/256 blocks of 256 (one i per thread).
__global__ __launch_bounds__(256) void kg1(
        const float* __restrict__ x, const float* __restrict__ lab,
        const float* __restrict__ e, const float* __restrict__ w,
        const float* __restrict__ RAp, const float* __restrict__ RBp,
        int n, int njs, const double* __restrict__ tpart, int ntp,
        double* __restrict__ spart) {
    __shared__ double lds[4];
    int t = threadIdx.x;
    int i = blockIdx.x * 256 + t;
    double rai = 0.0, rbi = 0.0;                     // double column-sum of partials
    for (int p = 0; p < njs; ++p) {
        rai += (double)RAp[(size_t)p * n + i];
        rbi += (double)RBp[(size_t)p * n + i];
    }
    double wi = (double)w[i];
    double xi = (double)x[i], ei = (double)e[i], yi = (double)lab[i];
    float xf = x[i];
    float sp = fmaxf(xf, 0.f) + log1pf(expf(-fabsf(xf)));   // stable softplus
    double acc[NSC];
    acc[0]  = wi;                    // W
    acc[1]  = ((double)sp - xi * yi) * wi;  // BCE sum
    acc[2]  = wi * rai * rbi;        // AB
    acc[3]  = wi * rai * rai;        // AA
    acc[4]  = wi * rbi * rbi;        // BB
    acc[5]  = wi * rai;              // CA
    acc[6]  = wi * rbi;              // CB
    acc[7]  = wi * xi;               // Sx
    acc[8]  = wi * xi * xi;          // Sxx
    acc[9]  = wi * ei;               // Se
    acc[10] = wi * ei * ei;          // See
    acc[11] = (i < ntp) ? tpart[i] : 0.0;   // T1ab partial fold-in
#pragma unroll
    for (int k = 0; k < NSC; ++k) {
        double r = blockReduceD(acc[k], lds);
        if (t == 0) spart[blockIdx.x * NSC + k] = r;
    }
}

// Combine 32 partials x 12 scalars, finalize. One block of NSC*32 threads.
__global__ __launch_bounds__(NSC * 32) void kg2(
        const double* __restrict__ spart, int nblk, int n, float* __restrict__ out) {
    __shared__ double sk[NSC];
    int t = threadIdx.x;
    int k = t >> 5, p = t & 31;
    double v = (k < NSC && p < nblk) ? spart[p * NSC + k] : 0.0;
    for (int off = 16; off > 0; off >>= 1) v += __shfl_down(v, off, 32);
    if (p == 0 && k < NSC) sk[k] = v;
    __syncthreads();
    if (t == 0) {
        double W = sk[0], BCE = sk[1], AB = sk[2], AA = sk[3], BB = sk[4];
        double CA = sk[5], CB = sk[6], Sx = sk[7], Sxx = sk[8];
        double Se = sk[9], See = sk[10], T1ab = sk[11];
        double N = (double)n;
        double T1aa = 2.0 * (W * Sxx - Sx * Sx);
        double T1bb = 2.0 * (W * See - Se * Se);
        double s = N / W, s2 = s * s, s3 = s2 * s, s4 = s2 * s2;
        double Sab = s2 * T1ab - (2.0 * s3 / N) * AB + (s4 / (N * N)) * CA * CB;
        double Saa = s2 * T1aa - (2.0 * s3 / N) * AA + (s4 / (N * N)) * CA * CA;
        double Sbb = s2 * T1bb - (2.0 * s3 / N) * BB + (s4 / (N * N)) * CB * CB;
        double disco = Sab / sqrt(Saa * Sbb);
        double bce = BCE / N;
        out[0] = (float)bce;
        out[1] = (float)disco;
        out[2] = (float)(bce + 0.1 * disco);
    }
}

extern "C" void kernel_launch(void* const* d_in, const int* in_sizes, int n_in,
                              void* d_out, int out_size, void* d_ws, size_t ws_size,
                              hipStream_t stream) {
    const float* outputs = (const float*)d_in[0];
    const float* labels  = (const float*)d_in[1];
    const float* event   = (const float*)d_in[2];
    const float* weights = (const float*)d_in[3];
    int n = in_sizes[0];

    int njs = n / JLEN;             // 128 j-splits
    int nit = n / (BLK * RPT);      // 8 i-tiles
    int ntp = njs * nit;            // 1024 T1ab partials
    int nblk1 = n / 256;            // 32

    double* tpart = (double*)d_ws;
    float* RAp = (float*)((char*)d_ws + 16384);
    float* RBp = RAp + (size_t)njs * n;
    double* spart = (double*)((char*)d_ws + 16384 + (size_t)2 * njs * n * sizeof(float));
    float* out = (float*)d_out;

    dim3 gF(nit, njs);              // (8, 128) = 1024 blocks
    kf<<<gF, BLK, 0, stream>>>(outputs, event, weights, n, tpart, RAp, RBp);
    kg1<<<nblk1, 256, 0, stream>>>(outputs, labels, event, weights, RAp, RBp,
                                   n, njs, tpart, ntp, spart);
    kg2<<<1, NSC * 32, 0, stream>>>(spart, nblk1, n, out);
}

// Round 6
// 89.986 us; speedup vs baseline: 1.2998x; 1.2998x over previous
//
#include <hip/hip_runtime.h>
#include <math.h>

// BCE + distance-correlation loss, N=8192 fp32.
//
// Expansion (raw weights w, W=sum w, s=N/W):
//   S_XY = s^2*T1xy - (2 s^3/N)*sum_i w_i RX_i RY_i + (s^4/N^2)*CX*CY
//   T1ab = sum_ij w_i w_j |x_i-x_j||e_i-e_j|        (needs N^2)
//   T1aa = 2(W*Sxx - Sx^2)   (closed form),  T1bb = 2(W*See - Se^2)
//   RX_i = sum_j w_j |x_i-x_j|,  CX = sum_i w_i RX_i
// kf: N^2 pass -> T1ab block partials + per-j-split float2 row partials.
// kg1: 32 blocks, ILP-unrolled column sum of partials + all 12 scalars.
// kg2: combine. No atomics, no memset, deterministic.
//
// ws: double tpart[1024] @0; float2 PP[128][N] @16K; double spart[32][12] after.

#define BLK  256
#define RPT  4     // rows/thread -> i-tile 1024
#define JLEN 64    // j-chunk per block -> 128 j-splits
#define NJS  128
#define NSC  12

__device__ inline double waveReduceD(double v) {
    for (int off = 32; off > 0; off >>= 1) v += __shfl_down(v, off, 64);
    return v;
}

// valid in threadIdx.x==0
__device__ inline double blockReduceD(double v, double* lds) {
    int lane = threadIdx.x & 63, wid = threadIdx.x >> 6;
    v = waveReduceD(v);
    if (lane == 0) lds[wid] = v;
    __syncthreads();
    double r = 0.0;
    if (wid == 0) {
        int nw = blockDim.x >> 6;
        r = (lane < nw) ? lds[lane] : 0.0;
        r = waveReduceD(r);
    }
    __syncthreads();
    return r;
}

// N^2 pass. grid = (n/(BLK*RPT), n/JLEN).
__global__ __launch_bounds__(BLK) void kf(
        const float* __restrict__ x, const float* __restrict__ e,
        const float* __restrict__ w, int n, double* __restrict__ tpart,
        float2* __restrict__ PP) {
    __shared__ float4 sj[JLEN];          // {x, e, w, 0} packed -> 1 b128 broadcast/k
    __shared__ double lds[BLK / 64];
    int t = threadIdx.x;
    int tj = blockIdx.y;
    int j0 = tj * JLEN;
    if (t < JLEN) {
        int j = j0 + t;
        sj[t] = make_float4(x[j], e[j], w[j], 0.f);
    }
    __syncthreads();

    int i0 = blockIdx.x * (BLK * RPT) + t;
    float xi[RPT], ei[RPT], ra[RPT], rb[RPT], ab[RPT];
#pragma unroll
    for (int r = 0; r < RPT; ++r) {
        int i = i0 + r * BLK;
        xi[r] = x[i]; ei[r] = e[i];
        ra[r] = 0.f; rb[r] = 0.f; ab[r] = 0.f;
    }

#pragma unroll 4
    for (int k = 0; k < JLEN; ++k) {
        float4 j4 = sj[k];                           // broadcast, conflict-free
        float xj = j4.x, ej = j4.y, wj = j4.z;
#pragma unroll
        for (int r = 0; r < RPT; ++r) {
            float a = fabsf(xi[r] - xj);
            float b = fabsf(ei[r] - ej);
            ra[r] = fmaf(wj, a, ra[r]);
            rb[r] = fmaf(wj, b, rb[r]);
            ab[r] = fmaf(wj, a * b, ab[r]);          // w_i applied below
        }
    }

    double tab = 0.0;
#pragma unroll
    for (int r = 0; r < RPT; ++r) {
        int i = i0 + r * BLK;
        tab += (double)(w[i] * ab[r]);
        PP[(size_t)tj * n + i] = make_float2(ra[r], rb[r]);  // coalesced 8B stores
    }
    tab = blockReduceD(tab, lds);
    if (t == 0) tpart[blockIdx.y * gridDim.x + blockIdx.x] = tab;
}

// Column-sum of partials + per-i scalars. grid = n/256 blocks.
__global__ __launch_bounds__(256) void kg1(
        const float* __restrict__ x, const float* __restrict__ lab,
        const float* __restrict__ e, const float* __restrict__ w,
        const float2* __restrict__ PP, int n,
        const double* __restrict__ tpart, int ntp,
        double* __restrict__ spart) {
    __shared__ double lds[4];
    int t = threadIdx.x;
    int i = blockIdx.x * 256 + t;

    double rai = 0.0, rbi = 0.0;
    // 16-deep load batches -> 16 outstanding 8B loads (latency hiding)
    for (int p0 = 0; p0 < NJS; p0 += 16) {
        float2 v[16];
#pragma unroll
        for (int q = 0; q < 16; ++q) v[q] = PP[(size_t)(p0 + q) * n + i];
#pragma unroll
        for (int q = 0; q < 16; ++q) { rai += (double)v[q].x; rbi += (double)v[q].y; }
    }

    double wi = (double)w[i];
    double xi = (double)x[i], ei = (double)e[i], yi = (double)lab[i];
    float xf = x[i];
    float sp = fmaxf(xf, 0.f) + log1pf(expf(-fabsf(xf)));   // stable softplus
    double acc[NSC];
    acc[0]  = wi;                    // W
    acc[1]  = ((double)sp - xi * yi) * wi;  // BCE sum
    acc[2]  = wi * rai * rbi;        // AB
    acc[3]  = wi * rai * rai;        // AA
    acc[4]  = wi * rbi * rbi;        // BB
    acc[5]  = wi * rai;              // CA
    acc[6]  = wi * rbi;              // CB
    acc[7]  = wi * xi;               // Sx
    acc[8]  = wi * xi * xi;          // Sxx
    acc[9]  = wi * ei;               // Se
    acc[10] = wi * ei * ei;          // See
    acc[11] = (i < ntp) ? tpart[i] : 0.0;   // T1ab partial fold-in
#pragma unroll
    for (int k = 0; k < NSC; ++k) {
        double r = blockReduceD(acc[k], lds);
        if (t == 0) spart[blockIdx.x * NSC + k] = r;
    }
}

// Combine 32 partials x 12 scalars, finalize. One block.
__global__ __launch_bounds__(NSC * 32) void kg2(
        const double* __restrict__ spart, int nblk, int n, float* __restrict__ out) {
    __shared__ double sk[NSC];
    int t = threadIdx.x;
    int k = t >> 5, p = t & 31;
    double v = (k < NSC && p < nblk) ? spart[p * NSC + k] : 0.0;
    for (int off = 16; off > 0; off >>= 1) v += __shfl_down(v, off, 32);
    if (p == 0 && k < NSC) sk[k] = v;
    __syncthreads();
    if (t == 0) {
        double W = sk[0], BCE = sk[1], AB = sk[2], AA = sk[3], BB = sk[4];
        double CA = sk[5], CB = sk[6], Sx = sk[7], Sxx = sk[8];
        double Se = sk[9], See = sk[10], T1ab = sk[11];
        double N = (double)n;
        double T1aa = 2.0 * (W * Sxx - Sx * Sx);
        double T1bb = 2.0 * (W * See - Se * Se);
        double s = N / W, s2 = s * s, s3 = s2 * s, s4 = s2 * s2;
        double Sab = s2 * T1ab - (2.0 * s3 / N) * AB + (s4 / (N * N)) * CA * CB;
        double Saa = s2 * T1aa - (2.0 * s3 / N) * AA + (s4 / (N * N)) * CA * CA;
        double Sbb = s2 * T1bb - (2.0 * s3 / N) * BB + (s4 / (N * N)) * CB * CB;
        double disco = Sab / sqrt(Saa * Sbb);
        double bce = BCE / N;
        out[0] = (float)bce;
        out[1] = (float)disco;
        out[2] = (float)(bce + 0.1 * disco);
    }
}

extern "C" void kernel_launch(void* const* d_in, const int* in_sizes, int n_in,
                              void* d_out, int out_size, void* d_ws, size_t ws_size,
                              hipStream_t stream) {
    const float* outputs = (const float*)d_in[0];
    const float* labels  = (const float*)d_in[1];
    const float* event   = (const float*)d_in[2];
    const float* weights = (const float*)d_in[3];
    int n = in_sizes[0];

    int nit = n / (BLK * RPT);      // 8 i-tiles
    int ntp = NJS * nit;            // 1024 T1ab partials
    int nblk1 = n / 256;            // 32

    double* tpart = (double*)d_ws;
    float2* PP = (float2*)((char*)d_ws + 16384);
    double* spart = (double*)((char*)d_ws + 16384 + (size_t)NJS * n * sizeof(float2));
    float* out = (float*)d_out;

    dim3 gF(nit, NJS);              // (8, 128) = 1024 blocks
    kf<<<gF, BLK, 0, stream>>>(outputs, event, weights, n, tpart, PP);
    kg1<<<nblk1, 256, 0, stream>>>(outputs, labels, event, weights, PP,
                                   n, tpart, ntp, spart);
    kg2<<<1, NSC * 32, 0, stream>>>(spart, nblk1, n, out);
}